// Round 8
// baseline (160.228 us; speedup 1.0000x reference)
//
#include <hip/hip_runtime.h>

#define EXTENT 7
#define CHANNELS 256
#define NPTS (EXTENT * EXTENT)  // 49

typedef float v4f __attribute__((ext_vector_type(4)));

// R3 structure (best: 4 blocks/box, 32 waves/CU) with ONE change: tap loads
// are non-temporal. Theory: harness poisons 256MiB (== L3 size) before every
// timed run, so L3 is 100% dirty; every cold fetch evicts a dirty victim ->
// hidden writeback tax (~2x per fetched byte). nt loads test whether we can
// skip L3 allocation and the tax.
__global__ __launch_bounds__(256) void roi_align_pyramid_kernel(
    const float* __restrict__ metadata,
    const float* __restrict__ boxes,
    const float* __restrict__ p2,
    const float* __restrict__ p3,
    const float* __restrict__ p4,
    const float* __restrict__ p5,
    float* __restrict__ out,
    int n_boxes)
{
    const int box = blockIdx.x % n_boxes;
    const int q   = blockIdx.x / n_boxes;      // 0..3
    const int tid = threadIdx.x;
    const int sub = (q << 2) | (tid >> 6);     // 0..15
    const int c   = (tid & 63) << 2;           // channel offset

    const float rows = metadata[0];
    const float cols = metadata[1];

    const float x1 = boxes[box * 4 + 0];
    const float y1 = boxes[box * 4 + 1];
    const float x2 = boxes[box * 4 + 2];
    const float y2 = boxes[box * 4 + 3];

    // Level selection — replicate reference fp32 math.
    const float h = y2 - y1;
    const float w = x2 - x1;
    float roi_level = logf(sqrtf(h * w) / sqrtf(rows * cols)) / logf(2.0f);
    roi_level = fminf(5.0f, fmaxf(2.0f, 4.0f + rintf(roi_level)));
    const int lvl = (int)roi_level;  // 2..5

    const float* feat;
    int H;
    if      (lvl == 2) { feat = p2; H = 256; }
    else if (lvl == 3) { feat = p3; H = 128; }
    else if (lvl == 4) { feat = p4; H = 64; }
    else               { feat = p5; H = 32; }
    const int W = H;

    const float ny1 = y1 / (rows - 1.0f);
    const float ny2 = y2 / (rows - 1.0f);
    const float nx1 = x1 / (cols - 1.0f);
    const float nx2 = x2 / (cols - 1.0f);

    float* outp = out + (size_t)box * NPTS * CHANNELS + c;

    auto process = [&](int p) {
        const int gy = p / EXTENT;
        const int gx = p - gy * EXTENT;

        const float gyf = (float)gy / (float)(EXTENT - 1);
        const float ysv = (ny1 + (ny2 - ny1) * gyf) * (float)(H - 1);
        float y0f = floorf(ysv);
        y0f = fminf(fmaxf(y0f, 0.0f), (float)(H - 2));
        const int   y0 = (int)y0f;
        const float wy = ysv - y0f;

        const float gxf = (float)gx / (float)(EXTENT - 1);
        const float xsv = (nx1 + (nx2 - nx1) * gxf) * (float)(W - 1);
        float x0f = floorf(xsv);
        x0f = fminf(fmaxf(x0f, 0.0f), (float)(W - 2));
        const int   x0 = (int)x0f;
        const float wx = xsv - x0f;

        const v4f* base = (const v4f*)(feat + ((size_t)(y0 * W + x0)) * CHANNELS + c);
        const int rowstep = (W * CHANNELS) / 4;  // v4f units per feature row
        const v4f f00 = __builtin_nontemporal_load(base);
        const v4f f01 = __builtin_nontemporal_load(base + CHANNELS / 4);
        const v4f f10 = __builtin_nontemporal_load(base + rowstep);
        const v4f f11 = __builtin_nontemporal_load(base + rowstep + CHANNELS / 4);

        const float w00 = (1.0f - wy) * (1.0f - wx);
        const float w01 = (1.0f - wy) * wx;
        const float w10 = wy * (1.0f - wx);
        const float w11 = wy * wx;

        v4f r = f00 * w00 + f01 * w01 + f10 * w10 + f11 * w11;

        __builtin_nontemporal_store(r, (v4f*)(outp + (size_t)p * CHANNELS));
    };

    // 49 points: sub + 16k for k in [0,3); p=48 by sub==0.
    #pragma unroll
    for (int k = 0; k < 3; ++k) {
        process(sub + 16 * k);
    }
    if (sub == 0) {
        process(48);
    }
}

extern "C" void kernel_launch(void* const* d_in, const int* in_sizes, int n_in,
                              void* d_out, int out_size, void* d_ws, size_t ws_size,
                              hipStream_t stream) {
    const float* metadata = (const float*)d_in[0];
    const float* boxes    = (const float*)d_in[1];
    const float* p2       = (const float*)d_in[2];
    const float* p3       = (const float*)d_in[3];
    const float* p4       = (const float*)d_in[4];
    const float* p5       = (const float*)d_in[5];
    float* out = (float*)d_out;

    const int n_boxes = in_sizes[1] / 4;  // 1024
    dim3 grid(n_boxes * 4);
    dim3 block(256);
    roi_align_pyramid_kernel<<<grid, block, 0, stream>>>(
        metadata, boxes, p2, p3, p4, p5, out, n_boxes);
}